// Round 1
// baseline (282.112 us; speedup 1.0000x reference)
//
#include <hip/hip_runtime.h>
#include <math.h>

#define WAVE 64

// ws header: hdr_i[0]=mw, hdr_i[1]=pad, hdr_i[2]=midx(k), hdr_f[3]=vmin, hdr_f[4]=vmax

__device__ __forceinline__ int bin_of(float x, float vmin, float scale, int NB) {
    int b = (int)((x - vmin) * scale);
    if (b < 0) b = 0;
    if (b > NB - 1) b = NB - 1;
    return b;
}

// ---------------------------------------------------------------------------
// Kernel 1: compute max_window via the tiny MLP (B=2, F=8, HID=16) + global
// min/max of attenuation. One wave.
// ---------------------------------------------------------------------------
__global__ void __launch_bounds__(64) k_params(
    const float* __restrict__ atten, const float* __restrict__ md,
    const float* __restrict__ w1, const float* __restrict__ b1,
    const float* __restrict__ w2, const float* __restrict__ b2,
    int* __restrict__ hdr_i, float* __restrict__ hdr_f,
    int T, int n_out, int nTot)
{
    int lane = threadIdx.x;
    int samples = 0;
    if (lane < 32) {                 // lane = b*16 + j
        int b = lane >> 4, j = lane & 15;
        float acc = b1[j];
        #pragma unroll
        for (int f = 0; f < 8; ++f) acc += md[b * 8 + f] * w1[f * 16 + j];
        float h = fmaxf(acc, 0.0f);
        float p = h * w2[j];
        #pragma unroll
        for (int off = 1; off < 16; off <<= 1) p += __shfl_xor(p, off);
        float s = p + b2[0];
        float factor = 1.0f / (1.0f + expf(-s));
        float hours = 4.0f + factor * (48.0f - 4.0f);
        samples = (int)(hours * 360.0f);   // trunc toward zero, matches astype(int32)
    }
    #pragma unroll
    for (int off = 1; off < 64; off <<= 1) samples = max(samples, __shfl_xor(samples, off));
    int mw = min(samples, T);

    // snap parity to the harness-fixed n_out (guards float roundoff of samples)
    int want_even = (n_out == T + 1) ? 1 : 0;
    if ((((mw & 1) == 0) ? 1 : 0) != want_even) { if (mw < T) mw += 1; else mw -= 1; }
    if (mw < 1) mw = 1;

    float vmin = 3.0e38f, vmax = -3.0e38f;
    for (int i = lane; i < nTot; i += WAVE) {
        float x = atten[i];
        vmin = fminf(vmin, x);
        vmax = fmaxf(vmax, x);
    }
    #pragma unroll
    for (int off = 1; off < 64; off <<= 1) {
        vmin = fminf(vmin, __shfl_xor(vmin, off));
        vmax = fmaxf(vmax, __shfl_xor(vmax, off));
    }
    if (lane == 0) {
        hdr_i[0] = mw;
        hdr_i[1] = mw >> 1;        // pad
        hdr_i[2] = (mw - 1) >> 1;  // midx = target rank k
        hdr_f[3] = vmin;
        hdr_f[4] = vmax;
    }
}

// ---------------------------------------------------------------------------
// Kernel 2: per-element bin index
// ---------------------------------------------------------------------------
__global__ void __launch_bounds__(256) k_bins(
    const float* __restrict__ atten, unsigned char* __restrict__ binIdx,
    const float* __restrict__ hdr_f, int nTot, int NB)
{
    int i = blockIdx.x * blockDim.x + threadIdx.x;
    if (i >= nTot) return;
    float vmin = hdr_f[3], vmax = hdr_f[4];
    float scale = (float)NB / fmaxf(vmax - vmin, 1e-10f);
    binIdx[i] = (unsigned char)bin_of(atten[i], vmin, scale, NB);
}

// ---------------------------------------------------------------------------
// Kernel 3: rank-prefix table. One wave per (batch, v): R[v][t] = #{i<t: bin<v},
// t in [0,T] inclusive. u16 (T=8640 < 65536).
// ---------------------------------------------------------------------------
__global__ void __launch_bounds__(64) k_rows(
    const unsigned char* __restrict__ binIdx, unsigned short* __restrict__ R,
    int T, int RS, int NB)
{
    int row = blockIdx.x;                 // b*(NB+1) + v
    int b = row / (NB + 1);
    int v = row - b * (NB + 1);
    const unsigned char* bi = binIdx + (size_t)b * T;
    unsigned short* r = R + (size_t)row * RS;
    int lane = threadIdx.x;
    int S = (T + WAVE - 1) / WAVE;
    int t0 = lane * S, t1 = min(T, t0 + S);

    int c = 0;
    for (int t = t0; t < t1; ++t) c += (bi[t] < v) ? 1 : 0;
    int incl = c;
    #pragma unroll
    for (int off = 1; off < 64; off <<= 1) {
        int n = __shfl_up(incl, off);
        if (lane >= off) incl += n;
    }
    int run = incl - c;                   // exclusive prefix
    for (int t = t0; t < t1; ++t) {
        r[t] = (unsigned short)run;
        run += (bi[t] < v) ? 1 : 0;
    }
    if (lane == 63) r[T] = (unsigned short)incl;   // total = bucket offsets
}

// ---------------------------------------------------------------------------
// Kernel 4: stable counting-sort scatter by bin: (value, pos) per slot
// ---------------------------------------------------------------------------
__global__ void __launch_bounds__(256) k_scatter(
    const float* __restrict__ atten, const unsigned char* __restrict__ binIdx,
    const unsigned short* __restrict__ R, float* __restrict__ bval,
    unsigned short* __restrict__ bpos, int T, int RS, int NB, int nTot)
{
    int i = blockIdx.x * blockDim.x + threadIdx.x;
    if (i >= nTot) return;
    int b = i / T;
    int t = i - b * T;
    int bn = binIdx[i];
    const unsigned short* Rb = R + (size_t)(b * (NB + 1)) * RS;
    int B0 = Rb[(size_t)bn * RS + T];                                   // # bins < bn overall
    int within = (int)Rb[(size_t)(bn + 1) * RS + t] - (int)Rb[(size_t)bn * RS + t]; // # same-bin before t
    int slot = B0 + within;
    bval[(size_t)b * T + slot] = atten[i];
    bpos[(size_t)b * T + slot] = (unsigned short)t;
}

// ---------------------------------------------------------------------------
// Kernel 5: one thread per output. Coarse bin via O(log NB) probes on R,
// window subrange in the bucket via pos binary search, then value bisection
// over ~100 candidates. Edge-pad replicas handled analytically.
// ---------------------------------------------------------------------------
__global__ void __launch_bounds__(256) k_query(
    const float* __restrict__ atten, const unsigned short* __restrict__ R,
    const float* __restrict__ bval, const unsigned short* __restrict__ bpos,
    const int* __restrict__ hdr_i, const float* __restrict__ hdr_f,
    float* __restrict__ out, int T, int n_out, int RS, int NB)
{
    int gid = blockIdx.x * blockDim.x + threadIdx.x;
    if (gid >= 2 * n_out) return;
    int b = gid / n_out;
    int o = gid - b * n_out;

    int mw = hdr_i[0], pad = hdr_i[1], k = hdr_i[2];
    float vmin = hdr_f[3], vmax = hdr_f[4];
    float range = fmaxf(vmax - vmin, 1e-10f);
    float scale = (float)NB / range;
    float binw = range / (float)NB;

    int lo_t = o - pad;
    int ta = max(lo_t, 0);
    int tb = min(lo_t + mw, T);
    int L  = ta - lo_t;            // left edge-pad copies of x[0]
    int Rr = (lo_t + mw) - tb;     // right edge-pad copies of x[T-1]

    const float* xb = atten + (size_t)b * T;
    float x0 = xb[0], xT = xb[T - 1];
    int b0 = bin_of(x0, vmin, scale, NB);
    int bT = bin_of(xT, vmin, scale, NB);

    const unsigned short* Rb = R + (size_t)(b * (NB + 1)) * RS;

    // coarse: smallest v with cnt(<v) >= k+1  ->  median bin = v-1
    int lov = 0, hiv = NB, clo = 0;
    while (hiv - lov > 1) {
        int mid = (lov + hiv) >> 1;
        const unsigned short* rm = Rb + (size_t)mid * RS;
        int c = (int)rm[tb] - (int)rm[ta];
        if (b0 < mid) c += L;
        if (bT < mid) c += Rr;
        if (c >= k + 1) hiv = mid;
        else { lov = mid; clo = c; }
    }
    int bsel = lov;
    int kp = k - clo;              // residual rank within selected bin

    int s0 = Rb[(size_t)bsel * RS + T];
    int s1 = Rb[(size_t)(bsel + 1) * RS + T];
    const unsigned short* bp = bpos + (size_t)b * T;
    const float* bv = bval + (size_t)b * T;

    int j0, j1e;
    { int lo = s0, hi = s1;
      while (lo < hi) { int m = (lo + hi) >> 1; if ((int)bp[m] < ta) lo = m + 1; else hi = m; }
      j0 = lo; }
    { int lo = j0, hi = s1;
      while (lo < hi) { int m = (lo + hi) >> 1; if ((int)bp[m] < tb) lo = m + 1; else hi = m; }
      j1e = lo; }

    int Lc = (b0 == bsel) ? L : 0;
    int Rc = (bT == bsel) ? Rr : 0;

    float vlo = vmin + (float)bsel * binw - binw;        // margin for quantize roundoff
    float vhi = vmin + (float)(bsel + 1) * binw + binw;
    for (int it = 0; it < 18; ++it) {
        float vm = 0.5f * (vlo + vhi);
        int c = 0;
        if (x0 < vm) c += Lc;
        if (xT < vm) c += Rc;
        for (int j = j0; j < j1e; ++j) c += (bv[j] < vm) ? 1 : 0;
        if (c >= kp + 1) vhi = vm; else vlo = vm;
    }
    out[(size_t)b * n_out + o] = 0.5f * (vlo + vhi);
}

// ---------------------------------------------------------------------------
// Fallback (tiny d_ws): one wave per output, 26-step value bisection with
// full-window counting. Correct but slow; only used if ws can't hold R.
// ---------------------------------------------------------------------------
__global__ void __launch_bounds__(256) k_fallback(
    const float* __restrict__ atten, const int* __restrict__ hdr_i,
    const float* __restrict__ hdr_f, float* __restrict__ out, int T, int n_out)
{
    int wave = threadIdx.x >> 6;
    int lane = threadIdx.x & 63;
    int gid = blockIdx.x * 4 + wave;
    if (gid >= 2 * n_out) return;
    int b = gid / n_out;
    int o = gid - b * n_out;
    int mw = hdr_i[0], pad = hdr_i[1], k = hdr_i[2];
    float lo = hdr_f[3] - 1e-3f, hi = hdr_f[4] + 1e-3f;
    const float* xb = atten + (size_t)b * T;
    int lo_t = o - pad;
    for (int it = 0; it < 26; ++it) {
        float vm = 0.5f * (lo + hi);
        int c = 0;
        for (int i = lane; i < mw; i += 64) {
            int t = lo_t + i;
            t = t < 0 ? 0 : (t >= T ? T - 1 : t);
            c += (xb[t] < vm) ? 1 : 0;
        }
        #pragma unroll
        for (int off = 1; off < 64; off <<= 1) c += __shfl_xor(c, off);
        if (c >= k + 1) hi = vm; else lo = vm;
    }
    if (lane == 0) out[(size_t)b * n_out + o] = 0.5f * (lo + hi);
}

extern "C" void kernel_launch(void* const* d_in, const int* in_sizes, int n_in,
                              void* d_out, int out_size, void* d_ws, size_t ws_size,
                              hipStream_t stream)
{
    const float* atten = (const float*)d_in[0];
    const float* md    = (const float*)d_in[1];
    const float* w1    = (const float*)d_in[2];
    const float* b1    = (const float*)d_in[3];
    const float* w2    = (const float*)d_in[4];
    const float* b2    = (const float*)d_in[5];
    float* out = (float*)d_out;

    const int B = 2, C = 1;
    const int nTot  = in_sizes[0];          // B*C*T
    const int T     = nTot / (B * C);
    const int n_out = out_size / (B * C);   // parity of mw is encoded here

    char* ws = (char*)d_ws;
    int*   hdr_i = (int*)ws;
    float* hdr_f = (float*)ws;

    auto align64 = [](size_t x) { return (x + 63) & ~(size_t)63; };
    const size_t RS = (size_t)T + 8;        // u16 row stride, keeps rows 4B-aligned
    const size_t offBin = 64;

    int NB = 0;
    size_t offR = 0, offBval = 0, offBpos = 0;
    const int tries[3] = {256, 64, 16};
    for (int ti = 0; ti < 3; ++ti) {
        int nbTry = tries[ti];
        size_t oR  = align64(offBin + (size_t)nTot);
        size_t rB  = (size_t)2 * (size_t)(nbTry + 1) * RS * 2;
        size_t oV  = align64(oR + rB);
        size_t oP  = align64(oV + (size_t)nTot * 4);
        size_t tot = align64(oP + (size_t)nTot * 2);
        if (ws_size >= tot) { NB = nbTry; offR = oR; offBval = oV; offBpos = oP; break; }
    }

    hipLaunchKernelGGL(k_params, dim3(1), dim3(64), 0, stream,
                       atten, md, w1, b1, w2, b2, hdr_i, hdr_f, T, n_out, nTot);

    if (NB == 0) {
        int blocks = (2 * n_out + 3) / 4;
        hipLaunchKernelGGL(k_fallback, dim3(blocks), dim3(256), 0, stream,
                           atten, hdr_i, hdr_f, out, T, n_out);
        return;
    }

    unsigned char*  binIdx = (unsigned char*)(ws + offBin);
    unsigned short* R      = (unsigned short*)(ws + offR);
    float*          bval   = (float*)(ws + offBval);
    unsigned short* bpos   = (unsigned short*)(ws + offBpos);

    int blocksE = (nTot + 255) / 256;
    hipLaunchKernelGGL(k_bins, dim3(blocksE), dim3(256), 0, stream,
                       atten, binIdx, hdr_f, nTot, NB);
    hipLaunchKernelGGL(k_rows, dim3(2 * (NB + 1)), dim3(64), 0, stream,
                       binIdx, R, T, (int)RS, NB);
    hipLaunchKernelGGL(k_scatter, dim3(blocksE), dim3(256), 0, stream,
                       atten, binIdx, R, bval, bpos, T, (int)RS, NB, nTot);
    int blocksQ = (2 * n_out + 255) / 256;
    hipLaunchKernelGGL(k_query, dim3(blocksQ), dim3(256), 0, stream,
                       atten, R, bval, bpos, hdr_i, hdr_f, out, T, n_out, (int)RS, NB);
}

// Round 2
// 212.210 us; speedup vs baseline: 1.3294x; 1.3294x over previous
//
#include <hip/hip_runtime.h>
#include <math.h>

// ws header: hdr_i[0]=mw, hdr_i[1]=pad, hdr_i[2]=midx(k), hdr_f[3]=vmin, hdr_f[4]=vmax

__device__ __forceinline__ int bin_of(float x, float vmin, float scale, int NB) {
    int v = (int)((x - vmin) * scale);
    return v < 0 ? 0 : (v > NB - 1 ? NB - 1 : v);
}

__device__ __forceinline__ void load16u16(const unsigned short* p, int* d) {
    uint4 a = *(const uint4*)p;
    uint4 b = *(const uint4*)(p + 8);
    unsigned w[8] = {a.x, a.y, a.z, a.w, b.x, b.y, b.z, b.w};
    #pragma unroll
    for (int i = 0; i < 8; ++i) { d[2*i] = (int)(w[i] & 0xFFFFu); d[2*i+1] = (int)(w[i] >> 16); }
}
__device__ __forceinline__ void load4u16(const unsigned short* p, int* d) {
    uint2 a = *(const uint2*)p;
    d[0] = (int)(a.x & 0xFFFFu); d[1] = (int)(a.x >> 16);
    d[2] = (int)(a.y & 0xFFFFu); d[3] = (int)(a.y >> 16);
}

// ---------------------------------------------------------------------------
// K1: parallel min/max reduction + tiny MLP (max_window). One 1024-thr block.
// ---------------------------------------------------------------------------
__global__ void __launch_bounds__(1024) k_setup(
    const float* __restrict__ atten, const float* __restrict__ md,
    const float* __restrict__ w1, const float* __restrict__ b1,
    const float* __restrict__ w2, const float* __restrict__ b2,
    int* __restrict__ hdr_i, float* __restrict__ hdr_f,
    int T, int n_out, int nTot)
{
    __shared__ float smin[16], smax[16];
    int tid = threadIdx.x;
    float vmin = 3.0e38f, vmax = -3.0e38f;
    for (int i = tid; i < nTot; i += 1024) {
        float x = atten[i];
        vmin = fminf(vmin, x); vmax = fmaxf(vmax, x);
    }
    #pragma unroll
    for (int off = 1; off < 64; off <<= 1) {
        vmin = fminf(vmin, __shfl_xor(vmin, off));
        vmax = fmaxf(vmax, __shfl_xor(vmax, off));
    }
    if ((tid & 63) == 0) { smin[tid >> 6] = vmin; smax[tid >> 6] = vmax; }
    __syncthreads();
    if (tid < 64) {
        int lane = tid;
        float m1 = (lane < 16) ? smin[lane] : 3.0e38f;
        float m2 = (lane < 16) ? smax[lane] : -3.0e38f;
        #pragma unroll
        for (int off = 1; off < 16; off <<= 1) {
            m1 = fminf(m1, __shfl_xor(m1, off));
            m2 = fmaxf(m2, __shfl_xor(m2, off));
        }
        int samples = 0;
        if (lane < 32) {                 // lane = b*16 + j
            int b = lane >> 4, j = lane & 15;
            float acc = b1[j];
            #pragma unroll
            for (int f = 0; f < 8; ++f) acc += md[b * 8 + f] * w1[f * 16 + j];
            float h = fmaxf(acc, 0.0f);
            float p = h * w2[j];
            #pragma unroll
            for (int off = 1; off < 16; off <<= 1) p += __shfl_xor(p, off);
            float s = p + b2[0];
            float factor = 1.0f / (1.0f + expf(-s));
            float hours = 4.0f + factor * (48.0f - 4.0f);
            samples = (int)(hours * 360.0f);
        }
        #pragma unroll
        for (int off = 1; off < 64; off <<= 1) samples = max(samples, __shfl_xor(samples, off));
        int mw = min(samples, T);
        // snap parity to harness-fixed n_out (guards float roundoff)
        int want_even = (n_out == T + 1) ? 1 : 0;
        if ((((mw & 1) == 0) ? 1 : 0) != want_even) { if (mw < T) mw += 1; else mw -= 1; }
        if (mw < 1) mw = 1;
        if (lane == 0) {
            hdr_i[0] = mw;
            hdr_i[1] = mw >> 1;
            hdr_i[2] = (mw - 1) >> 1;
            hdr_f[3] = m1;
            hdr_f[4] = m2;
        }
    }
}

// ---------------------------------------------------------------------------
// K2: per-tile (64 elems) binning + histogram. grid = 2*NTe, 64 thr.
// ---------------------------------------------------------------------------
template<int NB>
__global__ void __launch_bounds__(64) k_hist(
    const float* __restrict__ atten, unsigned char* __restrict__ binIdx,
    unsigned short* __restrict__ tileCnt, const float* __restrict__ hdr_f,
    int T, int NTe)
{
    int blk = blockIdx.x;
    int b = blk / NTe, tile = blk - b * NTe;
    __shared__ unsigned int hist[NB];
    int lane = threadIdx.x;
    #pragma unroll
    for (int j = lane; j < NB; j += 64) hist[j] = 0;
    __syncthreads();
    int t = tile * 64 + lane;
    if (t < T) {
        float vmin = hdr_f[3], vmax = hdr_f[4];
        float scale = (float)NB / fmaxf(vmax - vmin, 1e-10f);
        float x = atten[(size_t)b * T + t];
        int v = bin_of(x, vmin, scale, NB);
        binIdx[(size_t)b * T + t] = (unsigned char)v;
        atomicAdd(&hist[v], 1u);
    }
    __syncthreads();
    unsigned short* row = tileCnt + ((size_t)b * NTe + tile) * NB;
    #pragma unroll
    for (int j = lane; j < NB; j += 64) row[j] = (unsigned short)hist[j];
}

// ---------------------------------------------------------------------------
// K3: exclusive prefix over tiles (per bin). grid (NB/64, 2), 64 thr.
// ---------------------------------------------------------------------------
template<int NB>
__global__ void __launch_bounds__(64) k_base(
    const unsigned short* __restrict__ tileCnt, unsigned short* __restrict__ tileBase,
    int NTe, int NTr)
{
    int b = blockIdx.y;
    int v = blockIdx.x * 64 + threadIdx.x;
    const unsigned short* cnt = tileCnt + (size_t)b * NTe * NB + v;
    unsigned short* base = tileBase + (size_t)b * NTr * NB + v;
    unsigned int acc = 0;
    for (int r = 0; r < NTr; ++r) {
        base[(size_t)r * NB] = (unsigned short)acc;
        if (r < NTe) acc += cnt[(size_t)r * NB];
    }
}

// ---------------------------------------------------------------------------
// K4: write F[t][v] = #{i<t: bin<=v} (u16, contiguous row) and S[t][s]
//     (super-bin CDF). grid = 2*NTr, 64 thr. One wave slides its 64 records.
// ---------------------------------------------------------------------------
template<int NB>
__global__ void __launch_bounds__(64) k_cdf(
    const unsigned char* __restrict__ binIdx, const unsigned short* __restrict__ tileBase,
    unsigned short* __restrict__ F, unsigned short* __restrict__ S, int T, int NTr)
{
    constexpr int VPL = NB / 64;   // bins per lane (contiguous)
    constexpr int SB  = NB / 16;
    int blk = blockIdx.x;
    int b = blk / NTr, r = blk - b * NTr;
    int lane = threadIdx.x;
    int v0 = lane * VPL;

    const unsigned short* baserow = tileBase + ((size_t)b * NTr + r) * NB;
    int c[VPL];
    int loc = 0;
    #pragma unroll
    for (int kk = 0; kk < VPL; ++kk) { loc += (int)baserow[v0 + kk]; c[kk] = loc; }
    int incl = loc;
    #pragma unroll
    for (int off = 1; off < 64; off <<= 1) {
        int n = __shfl_up(incl, off);
        if (lane >= off) incl += n;
    }
    int excl = incl - loc;
    #pragma unroll
    for (int kk = 0; kk < VPL; ++kk) c[kk] += excl;   // inclusive CDF at bin v0+kk

    int t0 = r * 64, t1 = min(T + 1, t0 + 64);
    const unsigned char* bi = binIdx + (size_t)b * T;
    unsigned short* Fb = F + (size_t)b * (T + 1) * NB;
    unsigned short* Sb = S + (size_t)b * (T + 1) * SB;

    int myb = (t0 + lane < T) ? (int)bi[t0 + lane] : 0;   // element bins, shfl-broadcast

    bool writeS = (((v0 + VPL - 1) & 15) == 15);
    int sIdx = (v0 + VPL - 1) >> 4;

    for (int t = t0; t < t1; ++t) {
        unsigned short* Ft = Fb + (size_t)t * NB + v0;
        if (VPL == 4) {
            uint2 pk;
            pk.x = (unsigned)c[0] | ((unsigned)c[1] << 16);
            pk.y = (unsigned)c[2] | ((unsigned)c[VPL - 1] << 16);
            *(uint2*)Ft = pk;
        } else {
            Ft[0] = (unsigned short)c[0];
        }
        if (writeS) Sb[(size_t)t * SB + sIdx] = (unsigned short)c[VPL - 1];
        if (t < T) {
            int bt = __shfl(myb, t - t0);
            #pragma unroll
            for (int kk = 0; kk < VPL; ++kk) c[kk] += (v0 + kk >= bt) ? 1 : 0;
        }
    }
}

// ---------------------------------------------------------------------------
// K5: stable counting-sort scatter of values by (bin, t) -> bval.
// ---------------------------------------------------------------------------
template<int NB>
__global__ void __launch_bounds__(256) k_scatter(
    const float* __restrict__ atten, const unsigned char* __restrict__ binIdx,
    const unsigned short* __restrict__ F, float* __restrict__ bval, int T, int nTot)
{
    int i = blockIdx.x * 256 + threadIdx.x;
    if (i >= nTot) return;
    int b = i / T, t = i - b * T;
    int bn = binIdx[i];
    const unsigned short* Fb = F + (size_t)b * (T + 1) * NB;
    int s0   = bn ? (int)Fb[(size_t)T * NB + bn - 1] : 0;
    int FtB  = (int)Fb[(size_t)t * NB + bn];
    int FtP  = bn ? (int)Fb[(size_t)t * NB + bn - 1] : 0;
    bval[(size_t)b * T + (s0 + (FtB - FtP))] = atten[i];
}

// ---------------------------------------------------------------------------
// K6: query. 2 dependent hops (S row -> F group row), register scans,
//     arithmetic bucket range, short value bisection over ~mw/NB candidates.
// ---------------------------------------------------------------------------
template<int NB>
__global__ void __launch_bounds__(64) k_query(
    const float* __restrict__ atten, const unsigned short* __restrict__ F,
    const unsigned short* __restrict__ S, const float* __restrict__ bval,
    const int* __restrict__ hdr_i, const float* __restrict__ hdr_f,
    float* __restrict__ out, int T, int n_out)
{
    constexpr int SB = NB / 16;
    int gid = blockIdx.x * 64 + threadIdx.x;
    if (gid >= 2 * n_out) return;
    int b = gid / n_out, o = gid - b * n_out;

    int mw = hdr_i[0], pad = hdr_i[1], k = hdr_i[2];
    float vmin = hdr_f[3], vmax = hdr_f[4];
    float range = fmaxf(vmax - vmin, 1e-10f);
    float binw = range / (float)NB;
    float scale = (float)NB / range;

    int lo_t = o - pad;
    int ta = max(lo_t, 0);
    int tb = min(lo_t + mw, T);
    int L  = ta - lo_t;
    int Rr = lo_t + mw - tb;

    const float* xb = atten + (size_t)b * T;
    float x0 = xb[0], xT = xb[T - 1];
    int b0 = bin_of(x0, vmin, scale, NB);
    int bT = bin_of(xT, vmin, scale, NB);

    int sa[SB], sb[SB];
    {
        const unsigned short* pa = S + ((size_t)b * (T + 1) + ta) * SB;
        const unsigned short* pb = S + ((size_t)b * (T + 1) + tb) * SB;
        if (SB == 16) { load16u16(pa, sa); load16u16(pb, sb); }
        else          { load4u16(pa, sa);  load4u16(pb, sb); }
    }

    int kk = k + 1;
    int sb0 = b0 >> 4, sbT = bT >> 4;
    int ss = SB - 1, cprev = 0, saP = 0, sbP = 0;
    bool done1 = false;
    #pragma unroll
    for (int s = 0; s < SB; ++s) {
        int c = sb[s] - sa[s] + (sb0 <= s ? L : 0) + (sbT <= s ? Rr : 0);
        if (!done1 && c >= kk) { ss = s; done1 = true; }
        if (!done1) { cprev = c; saP = sa[s]; sbP = sb[s]; }
    }

    int fa[16], fb[16];
    {
        const unsigned short* pa = F + ((size_t)b * (T + 1) + ta) * NB + ss * 16;
        const unsigned short* pb = F + ((size_t)b * (T + 1) + tb) * NB + ss * 16;
        load16u16(pa, fa); load16u16(pb, fb);
    }

    int vb = ss * 16;
    int jj = 15, wprev = cprev;
    int pA = ss ? saP : 0;    // F[ta][vb-1]
    int pB = ss ? sbP : 0;    // F[tb][vb-1]
    int faSel = fa[15], fbSel = fb[15];
    bool done2 = false;
    #pragma unroll
    for (int j = 0; j < 16; ++j) {
        int v = vb + j;
        int w = fb[j] - fa[j] + (b0 <= v ? L : 0) + (bT <= v ? Rr : 0);
        if (!done2 && w >= kk) { jj = j; done2 = true; faSel = fa[j]; fbSel = fb[j]; }
        if (!done2) { wprev = w; pA = fa[j]; pB = fb[j]; }
    }
    int bsel = vb + jj;
    int kp = k - wprev;

    int withinA = faSel - pA;
    int cntw = (fbSel - pB) - withinA;
    const unsigned short* FT = F + ((size_t)b * (T + 1) + T) * NB;
    int s0 = bsel ? (int)FT[bsel - 1] : 0;
    int j0 = s0 + withinA;
    int j1e = j0 + cntw;

    int Lc = (b0 == bsel) ? L : 0;
    int Rc = (bT == bsel) ? Rr : 0;

    const float* bv = bval + (size_t)b * T;
    float vlo = vmin + (float)bsel * binw - binw;
    float vhi = vmin + (float)(bsel + 1) * binw + binw;
    for (int it = 0; it < 15; ++it) {
        float vm = 0.5f * (vlo + vhi);
        int c = 0;
        if (x0 < vm) c += Lc;
        if (xT < vm) c += Rc;
        for (int j = j0; j < j1e; ++j) c += (bv[j] < vm) ? 1 : 0;
        if (c >= kp + 1) vhi = vm; else vlo = vm;
    }
    out[(size_t)b * n_out + o] = 0.5f * (vlo + vhi);
}

// ---------------------------------------------------------------------------
// Fallback (tiny d_ws): wave-per-output value bisection. Correct but slow.
// ---------------------------------------------------------------------------
__global__ void __launch_bounds__(256) k_fallback(
    const float* __restrict__ atten, const int* __restrict__ hdr_i,
    const float* __restrict__ hdr_f, float* __restrict__ out, int T, int n_out)
{
    int wave = threadIdx.x >> 6;
    int lane = threadIdx.x & 63;
    int gid = blockIdx.x * 4 + wave;
    if (gid >= 2 * n_out) return;
    int b = gid / n_out;
    int o = gid - b * n_out;
    int mw = hdr_i[0], pad = hdr_i[1], k = hdr_i[2];
    float lo = hdr_f[3] - 1e-3f, hi = hdr_f[4] + 1e-3f;
    const float* xb = atten + (size_t)b * T;
    int lo_t = o - pad;
    for (int it = 0; it < 26; ++it) {
        float vm = 0.5f * (lo + hi);
        int c = 0;
        for (int i = lane; i < mw; i += 64) {
            int t = lo_t + i;
            t = t < 0 ? 0 : (t >= T ? T - 1 : t);
            c += (xb[t] < vm) ? 1 : 0;
        }
        #pragma unroll
        for (int off = 1; off < 64; off <<= 1) c += __shfl_xor(c, off);
        if (c >= k + 1) hi = vm; else lo = vm;
    }
    if (lane == 0) out[(size_t)b * n_out + o] = 0.5f * (lo + hi);
}

// ---------------------------------------------------------------------------
struct Plan {
    size_t oBin, oCnt, oBase, oF, oS, oV, total;
};
static Plan make_plan(int NB, int nTot, int T, int NTe, int NTr) {
    auto a64 = [](size_t x) { return (x + 63) & ~(size_t)63; };
    Plan p;
    size_t off = 64;
    p.oBin  = off; off = a64(off + (size_t)nTot);
    p.oCnt  = off; off = a64(off + (size_t)2 * NTe * NB * 2);
    p.oBase = off; off = a64(off + (size_t)2 * NTr * NB * 2);
    p.oF    = off; off = a64(off + (size_t)2 * (T + 1) * NB * 2);
    p.oS    = off; off = a64(off + (size_t)2 * (T + 1) * (NB / 16) * 2);
    p.oV    = off; off = a64(off + (size_t)nTot * 4);
    p.total = off;
    return p;
}

template<int NB>
static void run_pipeline(const float* atten, char* ws, const Plan& p,
                         const int* hdr_i, const float* hdr_f, float* out,
                         int T, int n_out, int nTot, int NTe, int NTr,
                         hipStream_t stream)
{
    unsigned char*  binIdx   = (unsigned char*)(ws + p.oBin);
    unsigned short* tileCnt  = (unsigned short*)(ws + p.oCnt);
    unsigned short* tileBase = (unsigned short*)(ws + p.oBase);
    unsigned short* F        = (unsigned short*)(ws + p.oF);
    unsigned short* S        = (unsigned short*)(ws + p.oS);
    float*          bval     = (float*)(ws + p.oV);

    k_hist<NB><<<dim3(2 * NTe), dim3(64), 0, stream>>>(atten, binIdx, tileCnt, hdr_f, T, NTe);
    k_base<NB><<<dim3(NB / 64, 2), dim3(64), 0, stream>>>(tileCnt, tileBase, NTe, NTr);
    k_cdf<NB><<<dim3(2 * NTr), dim3(64), 0, stream>>>(binIdx, tileBase, F, S, T, NTr);
    k_scatter<NB><<<dim3((nTot + 255) / 256), dim3(256), 0, stream>>>(atten, binIdx, F, bval, T, nTot);
    k_query<NB><<<dim3((2 * n_out + 63) / 64), dim3(64), 0, stream>>>(atten, F, S, bval, hdr_i, hdr_f, out, T, n_out);
}

extern "C" void kernel_launch(void* const* d_in, const int* in_sizes, int n_in,
                              void* d_out, int out_size, void* d_ws, size_t ws_size,
                              hipStream_t stream)
{
    const float* atten = (const float*)d_in[0];
    const float* md    = (const float*)d_in[1];
    const float* w1    = (const float*)d_in[2];
    const float* b1    = (const float*)d_in[3];
    const float* w2    = (const float*)d_in[4];
    const float* b2    = (const float*)d_in[5];
    float* out = (float*)d_out;

    const int B = 2;
    const int nTot  = in_sizes[0];
    const int T     = nTot / B;
    const int n_out = out_size / B;
    const int NTe = (T + 63) / 64;        // element tiles
    const int NTr = (T + 64) / 64;        // record tiles: ceil((T+1)/64)

    char* ws = (char*)d_ws;
    int*   hdr_i = (int*)ws;
    float* hdr_f = (float*)ws;

    k_setup<<<dim3(1), dim3(1024), 0, stream>>>(atten, md, w1, b1, w2, b2,
                                                hdr_i, hdr_f, T, n_out, nTot);

    Plan p256 = make_plan(256, nTot, T, NTe, NTr);
    Plan p64  = make_plan(64,  nTot, T, NTe, NTr);
    if (ws_size >= p256.total) {
        run_pipeline<256>(atten, ws, p256, hdr_i, hdr_f, out, T, n_out, nTot, NTe, NTr, stream);
    } else if (ws_size >= p64.total) {
        run_pipeline<64>(atten, ws, p64, hdr_i, hdr_f, out, T, n_out, nTot, NTe, NTr, stream);
    } else {
        int blocks = (2 * n_out + 3) / 4;
        k_fallback<<<dim3(blocks), dim3(256), 0, stream>>>(atten, hdr_i, hdr_f, out, T, n_out);
    }
}

// Round 3
// 132.804 us; speedup vs baseline: 2.1243x; 1.5979x over previous
//
#include <hip/hip_runtime.h>
#include <math.h>

// ws header: hdr_i[0]=mw, hdr_i[1]=pad, hdr_i[2]=midx(k), hdr_f[3]=vmin, hdr_f[4]=vmax

__device__ __forceinline__ int bin_of(float x, float vmin, float scale, int NB) {
    int v = (int)((x - vmin) * scale);
    return v < 0 ? 0 : (v > NB - 1 ? NB - 1 : v);
}

// ---------------------------------------------------------------------------
// K1: parallel min/max reduction + tiny MLP (max_window). One 1024-thr block.
// ---------------------------------------------------------------------------
__global__ void __launch_bounds__(1024) k_setup(
    const float* __restrict__ atten, const float* __restrict__ md,
    const float* __restrict__ w1, const float* __restrict__ b1,
    const float* __restrict__ w2, const float* __restrict__ b2,
    int* __restrict__ hdr_i, float* __restrict__ hdr_f,
    int T, int n_out, int nTot)
{
    __shared__ float smin[16], smax[16];
    int tid = threadIdx.x;
    float vmin = 3.0e38f, vmax = -3.0e38f;
    for (int i = tid; i < nTot; i += 1024) {
        float x = atten[i];
        vmin = fminf(vmin, x); vmax = fmaxf(vmax, x);
    }
    #pragma unroll
    for (int off = 1; off < 64; off <<= 1) {
        vmin = fminf(vmin, __shfl_xor(vmin, off));
        vmax = fmaxf(vmax, __shfl_xor(vmax, off));
    }
    if ((tid & 63) == 0) { smin[tid >> 6] = vmin; smax[tid >> 6] = vmax; }
    __syncthreads();
    if (tid < 64) {
        int lane = tid;
        float m1 = (lane < 16) ? smin[lane] : 3.0e38f;
        float m2 = (lane < 16) ? smax[lane] : -3.0e38f;
        #pragma unroll
        for (int off = 1; off < 16; off <<= 1) {
            m1 = fminf(m1, __shfl_xor(m1, off));
            m2 = fmaxf(m2, __shfl_xor(m2, off));
        }
        int samples = 0;
        if (lane < 32) {                 // lane = b*16 + j
            int b = lane >> 4, j = lane & 15;
            float acc = b1[j];
            #pragma unroll
            for (int f = 0; f < 8; ++f) acc += md[b * 8 + f] * w1[f * 16 + j];
            float h = fmaxf(acc, 0.0f);
            float p = h * w2[j];
            #pragma unroll
            for (int off = 1; off < 16; off <<= 1) p += __shfl_xor(p, off);
            float s = p + b2[0];
            float factor = 1.0f / (1.0f + expf(-s));
            float hours = 4.0f + factor * (48.0f - 4.0f);
            samples = (int)(hours * 360.0f);
        }
        #pragma unroll
        for (int off = 1; off < 64; off <<= 1) samples = max(samples, __shfl_xor(samples, off));
        int mw = min(samples, T);
        // snap parity to harness-fixed n_out (guards float roundoff)
        int want_even = (n_out == T + 1) ? 1 : 0;
        if ((((mw & 1) == 0) ? 1 : 0) != want_even) { if (mw < T) mw += 1; else mw -= 1; }
        if (mw < 1) mw = 1;
        if (lane == 0) {
            hdr_i[0] = mw;
            hdr_i[1] = mw >> 1;
            hdr_i[2] = (mw - 1) >> 1;
            hdr_f[3] = m1;
            hdr_f[4] = m2;
        }
    }
}

// ---------------------------------------------------------------------------
// K2: per-tile (64 elems) binning + histogram. grid = 2*NTe, 64 thr.
// ---------------------------------------------------------------------------
template<int NB>
__global__ void __launch_bounds__(64) k_hist(
    const float* __restrict__ atten, unsigned char* __restrict__ binIdx,
    unsigned short* __restrict__ tileCnt, const float* __restrict__ hdr_f,
    int T, int NTe)
{
    int blk = blockIdx.x;
    int b = blk / NTe, tile = blk - b * NTe;
    __shared__ unsigned int hist[NB];
    int lane = threadIdx.x;
    #pragma unroll
    for (int j = lane; j < NB; j += 64) hist[j] = 0;
    __syncthreads();
    int t = tile * 64 + lane;
    if (t < T) {
        float vmin = hdr_f[3], vmax = hdr_f[4];
        float scale = (float)NB / fmaxf(vmax - vmin, 1e-10f);
        float x = atten[(size_t)b * T + t];
        int v = bin_of(x, vmin, scale, NB);
        binIdx[(size_t)b * T + t] = (unsigned char)v;
        atomicAdd(&hist[v], 1u);
    }
    __syncthreads();
    unsigned short* row = tileCnt + ((size_t)b * NTe + tile) * NB;
    #pragma unroll
    for (int j = lane; j < NB; j += 64) row[j] = (unsigned short)hist[j];
}

// ---------------------------------------------------------------------------
// K3: fused tile-prefix + CDF writer. grid = 2*NTr, 64 thr.
// F[t][v] = #{i<t: bin<=v} (u16, contiguous 2*NB-byte row).
// ---------------------------------------------------------------------------
template<int NB>
__global__ void __launch_bounds__(64) k_cdf(
    const unsigned char* __restrict__ binIdx, const unsigned short* __restrict__ tileCnt,
    unsigned short* __restrict__ F, int T, int NTe, int NTr)
{
    constexpr int VPL = NB / 64;   // bins per lane (contiguous)
    int blk = blockIdx.x;
    int b = blk / NTr, r = blk - b * NTr;
    int lane = threadIdx.x;
    int v0 = lane * VPL;

    // per-lane bin totals over tiles < r (coalesced 512B rows)
    int bs[VPL];
    #pragma unroll
    for (int kk = 0; kk < VPL; ++kk) bs[kk] = 0;
    const unsigned short* cb = tileCnt + (size_t)b * NTe * NB + v0;
    int rmax = r < NTe ? r : NTe;
    for (int rp = 0; rp < rmax; ++rp) {
        if (VPL == 4) {
            uint2 u = *(const uint2*)(cb + (size_t)rp * NB);
            bs[0] += (int)(u.x & 0xFFFFu); bs[1] += (int)(u.x >> 16);
            bs[2] += (int)(u.y & 0xFFFFu); bs[VPL - 1] += (int)(u.y >> 16);
        } else {
            bs[0] += (int)cb[(size_t)rp * NB];
        }
    }
    // inclusive scan over bins: local + wave prefix
    int c[VPL];
    int loc = 0;
    #pragma unroll
    for (int kk = 0; kk < VPL; ++kk) { loc += bs[kk]; c[kk] = loc; }
    int incl = loc;
    #pragma unroll
    for (int off = 1; off < 64; off <<= 1) {
        int n = __shfl_up(incl, off);
        if (lane >= off) incl += n;
    }
    int excl = incl - loc;
    #pragma unroll
    for (int kk = 0; kk < VPL; ++kk) c[kk] += excl;   // F[t0][v0+kk]

    int t0 = r * 64, t1 = min(T + 1, t0 + 64);
    const unsigned char* bi = binIdx + (size_t)b * T;
    unsigned short* Fb = F + (size_t)b * (T + 1) * NB;

    int myb = (t0 + lane < T) ? (int)bi[t0 + lane] : 0;   // shfl-broadcast source

    for (int t = t0; t < t1; ++t) {
        unsigned short* Ft = Fb + (size_t)t * NB + v0;
        if (VPL == 4) {
            uint2 pk;
            pk.x = (unsigned)c[0] | ((unsigned)c[1] << 16);
            pk.y = (unsigned)c[2] | ((unsigned)c[VPL - 1] << 16);
            *(uint2*)Ft = pk;
        } else {
            Ft[0] = (unsigned short)c[0];
        }
        if (t < T) {
            int bt = __shfl(myb, t - t0);
            #pragma unroll
            for (int kk = 0; kk < VPL; ++kk) c[kk] += (v0 + kk >= bt) ? 1 : 0;
        }
    }
}

// ---------------------------------------------------------------------------
// K4: stable counting-sort scatter of values by (bin, t) -> bval.
// ---------------------------------------------------------------------------
template<int NB>
__global__ void __launch_bounds__(256) k_scatter(
    const float* __restrict__ atten, const unsigned char* __restrict__ binIdx,
    const unsigned short* __restrict__ F, float* __restrict__ bval, int T, int nTot)
{
    int i = blockIdx.x * 256 + threadIdx.x;
    if (i >= nTot) return;
    int b = i / T, t = i - b * T;
    int bn = binIdx[i];
    const unsigned short* Fb = F + (size_t)b * (T + 1) * NB;
    int s0   = bn ? (int)Fb[(size_t)T * NB + bn - 1] : 0;
    int FtB  = (int)Fb[(size_t)t * NB + bn];
    int FtP  = bn ? (int)Fb[(size_t)t * NB + bn - 1] : 0;
    bval[(size_t)b * T + (s0 + (FtB - FtP))] = atten[i];
}

// ---------------------------------------------------------------------------
// K5: wave-per-output query. Whole F rows at ta/tb loaded coalesced (VPL
// bins/lane), ballot bin-select, register candidates, ballot bisection.
// ---------------------------------------------------------------------------
template<int NB>
__global__ void __launch_bounds__(256) k_query(
    const float* __restrict__ atten, const unsigned short* __restrict__ F,
    const float* __restrict__ bval,
    const int* __restrict__ hdr_i, const float* __restrict__ hdr_f,
    float* __restrict__ out, int T, int n_out)
{
    constexpr int VPL = NB / 64;
    int wid = (blockIdx.x * 256 + threadIdx.x) >> 6;   // global wave id (uniform/wave)
    int lane = threadIdx.x & 63;
    if (wid >= 2 * n_out) return;
    int b = wid / n_out, o = wid - b * n_out;

    int mw = hdr_i[0], pad = hdr_i[1], k = hdr_i[2];
    float vmin = hdr_f[3], vmax = hdr_f[4];
    float range = fmaxf(vmax - vmin, 1e-10f);
    float binw = range / (float)NB;
    float scale = (float)NB / range;

    int lo_t = o - pad;
    int ta = max(lo_t, 0);
    int tb = min(lo_t + mw, T);
    int L  = ta - lo_t;
    int Rr = lo_t + mw - tb;

    const float* xb = atten + (size_t)b * T;
    float x0 = xb[0], xT = xb[T - 1];
    int b0 = bin_of(x0, vmin, scale, NB);
    int bT = bin_of(xT, vmin, scale, NB);

    const unsigned short* Fb = F + (size_t)b * (T + 1) * NB;
    int fa[VPL], fb[VPL];
    {
        const unsigned short* pa = Fb + (size_t)ta * NB + lane * VPL;
        const unsigned short* pb = Fb + (size_t)tb * NB + lane * VPL;
        if (VPL == 4) {
            uint2 ua = *(const uint2*)pa;
            fa[0] = (int)(ua.x & 0xFFFFu); fa[1] = (int)(ua.x >> 16);
            fa[2] = (int)(ua.y & 0xFFFFu); fa[VPL - 1] = (int)(ua.y >> 16);
            uint2 ub = *(const uint2*)pb;
            fb[0] = (int)(ub.x & 0xFFFFu); fb[1] = (int)(ub.x >> 16);
            fb[2] = (int)(ub.y & 0xFFFFu); fb[VPL - 1] = (int)(ub.y >> 16);
        } else {
            fa[0] = (int)pa[0]; fb[0] = (int)pb[0];
        }
    }

    int kk = k + 1;
    int w[VPL];
    #pragma unroll
    for (int j = 0; j < VPL; ++j) {
        int v = lane * VPL + j;
        w[j] = fb[j] - fa[j] + (b0 <= v ? L : 0) + (bT <= v ? Rr : 0);
    }
    unsigned long long m = __ballot(w[VPL - 1] >= kk);   // nonzero: top bin count = mw >= kk
    int ll = (int)__ffsll(m) - 1;

    int wj[VPL], faj[VPL], fbj[VPL];
    #pragma unroll
    for (int j = 0; j < VPL; ++j) {
        wj[j]  = __shfl(w[j], ll);
        faj[j] = __shfl(fa[j], ll);
        fbj[j] = __shfl(fb[j], ll);
    }
    int wprevL  = __shfl(w[VPL - 1], ll - 1);
    int faPrevL = __shfl(fa[VPL - 1], ll - 1);
    int fbPrevL = __shfl(fb[VPL - 1], ll - 1);
    if (ll == 0) { wprevL = 0; faPrevL = 0; fbPrevL = 0; }

    int jj = VPL - 1;
    #pragma unroll
    for (int j = VPL - 1; j >= 0; --j) if (wj[j] >= kk) jj = j;
    int bsel = ll * VPL + jj;
    int wprev = jj > 0 ? wj[jj - 1] : wprevL;
    int faSel = faj[jj], fbSel = fbj[jj];
    int pA = jj > 0 ? faj[jj - 1] : faPrevL;
    int pB = jj > 0 ? fbj[jj - 1] : fbPrevL;

    int kp = k - wprev;
    int withinA = faSel - pA;
    int cntw = (fbSel - pB) - withinA;
    int s0 = bsel ? (int)Fb[(size_t)T * NB + bsel - 1] : 0;   // broadcast load
    int j0 = s0 + withinA;
    int j1e = j0 + cntw;

    int Lc = (b0 == bsel) ? L : 0;
    int Rc = (bT == bsel) ? Rr : 0;

    const float* bv = bval + (size_t)b * T;
    float vlo = vmin + (float)bsel * binw - binw;
    float vhi = vmin + (float)(bsel + 1) * binw + binw;

    const int CAND = 4;
    float rr[CAND];
    bool reg = (cntw <= 64 * CAND);
    if (reg) {
        #pragma unroll
        for (int q = 0; q < CAND; ++q) {
            int idx = j0 + lane + q * 64;
            rr[q] = (idx < j1e) ? bv[idx] : 3.0e38f;
        }
    }
    int need = kp + 1;
    for (int it = 0; it < 18; ++it) {
        float vm = 0.5f * (vlo + vhi);
        int cnt = ((x0 < vm) ? Lc : 0) + ((xT < vm) ? Rc : 0);
        if (reg) {
            #pragma unroll
            for (int q = 0; q < CAND; ++q)
                cnt += __popcll(__ballot(rr[q] < vm));
        } else {
            int my = 0;
            for (int j = j0 + lane; j < j1e; j += 64) my += (bv[j] < vm) ? 1 : 0;
            #pragma unroll
            for (int off = 1; off < 64; off <<= 1) my += __shfl_xor(my, off);
            cnt += my;
        }
        if (cnt >= need) vhi = vm; else vlo = vm;
    }
    if (lane == 0) out[(size_t)b * n_out + o] = 0.5f * (vlo + vhi);
}

// ---------------------------------------------------------------------------
// Fallback (tiny d_ws): wave-per-output value bisection. Correct but slow.
// ---------------------------------------------------------------------------
__global__ void __launch_bounds__(256) k_fallback(
    const float* __restrict__ atten, const int* __restrict__ hdr_i,
    const float* __restrict__ hdr_f, float* __restrict__ out, int T, int n_out)
{
    int wave = threadIdx.x >> 6;
    int lane = threadIdx.x & 63;
    int gid = blockIdx.x * 4 + wave;
    if (gid >= 2 * n_out) return;
    int b = gid / n_out;
    int o = gid - b * n_out;
    int mw = hdr_i[0], pad = hdr_i[1], k = hdr_i[2];
    float lo = hdr_f[3] - 1e-3f, hi = hdr_f[4] + 1e-3f;
    const float* xb = atten + (size_t)b * T;
    int lo_t = o - pad;
    for (int it = 0; it < 26; ++it) {
        float vm = 0.5f * (lo + hi);
        int c = 0;
        for (int i = lane; i < mw; i += 64) {
            int t = lo_t + i;
            t = t < 0 ? 0 : (t >= T ? T - 1 : t);
            c += (xb[t] < vm) ? 1 : 0;
        }
        #pragma unroll
        for (int off = 1; off < 64; off <<= 1) c += __shfl_xor(c, off);
        if (c >= k + 1) hi = vm; else lo = vm;
    }
    if (lane == 0) out[(size_t)b * n_out + o] = 0.5f * (lo + hi);
}

// ---------------------------------------------------------------------------
struct Plan { size_t oBin, oCnt, oF, oV, total; };
static Plan make_plan(int NB, int nTot, int T, int NTe) {
    auto a64 = [](size_t x) { return (x + 63) & ~(size_t)63; };
    Plan p;
    size_t off = 64;
    p.oBin = off; off = a64(off + (size_t)nTot);
    p.oCnt = off; off = a64(off + (size_t)2 * NTe * NB * 2);
    p.oF   = off; off = a64(off + (size_t)2 * (T + 1) * NB * 2);
    p.oV   = off; off = a64(off + (size_t)nTot * 4);
    p.total = off;
    return p;
}

template<int NB>
static void run_pipeline(const float* atten, char* ws, const Plan& p,
                         const int* hdr_i, const float* hdr_f, float* out,
                         int T, int n_out, int nTot, int NTe, int NTr,
                         hipStream_t stream)
{
    unsigned char*  binIdx  = (unsigned char*)(ws + p.oBin);
    unsigned short* tileCnt = (unsigned short*)(ws + p.oCnt);
    unsigned short* F       = (unsigned short*)(ws + p.oF);
    float*          bval    = (float*)(ws + p.oV);

    k_hist<NB><<<dim3(2 * NTe), dim3(64), 0, stream>>>(atten, binIdx, tileCnt, hdr_f, T, NTe);
    k_cdf<NB><<<dim3(2 * NTr), dim3(64), 0, stream>>>(binIdx, tileCnt, F, T, NTe, NTr);
    k_scatter<NB><<<dim3((nTot + 255) / 256), dim3(256), 0, stream>>>(atten, binIdx, F, bval, T, nTot);
    int nWaves = 2 * n_out;
    k_query<NB><<<dim3((nWaves + 3) / 4), dim3(256), 0, stream>>>(atten, F, bval, hdr_i, hdr_f, out, T, n_out);
}

extern "C" void kernel_launch(void* const* d_in, const int* in_sizes, int n_in,
                              void* d_out, int out_size, void* d_ws, size_t ws_size,
                              hipStream_t stream)
{
    const float* atten = (const float*)d_in[0];
    const float* md    = (const float*)d_in[1];
    const float* w1    = (const float*)d_in[2];
    const float* b1    = (const float*)d_in[3];
    const float* w2    = (const float*)d_in[4];
    const float* b2    = (const float*)d_in[5];
    float* out = (float*)d_out;

    const int B = 2;
    const int nTot  = in_sizes[0];
    const int T     = nTot / B;
    const int n_out = out_size / B;
    const int NTe = (T + 63) / 64;        // element tiles
    const int NTr = (T + 64) / 64;        // record tiles: ceil((T+1)/64)

    char* ws = (char*)d_ws;
    int*   hdr_i = (int*)ws;
    float* hdr_f = (float*)ws;

    k_setup<<<dim3(1), dim3(1024), 0, stream>>>(atten, md, w1, b1, w2, b2,
                                                hdr_i, hdr_f, T, n_out, nTot);

    Plan p256 = make_plan(256, nTot, T, NTe);
    Plan p64  = make_plan(64,  nTot, T, NTe);
    if (ws_size >= p256.total) {
        run_pipeline<256>(atten, ws, p256, hdr_i, hdr_f, out, T, n_out, nTot, NTe, NTr, stream);
    } else if (ws_size >= p64.total) {
        run_pipeline<64>(atten, ws, p64, hdr_i, hdr_f, out, T, n_out, nTot, NTe, NTr, stream);
    } else {
        int blocks = (2 * n_out + 3) / 4;
        k_fallback<<<dim3(blocks), dim3(256), 0, stream>>>(atten, hdr_i, hdr_f, out, T, n_out);
    }
}

// Round 4
// 129.325 us; speedup vs baseline: 2.1814x; 1.0269x over previous
//
#include <hip/hip_runtime.h>
#include <math.h>

// ws header: hdr_i[0]=mw, hdr_i[1]=pad, hdr_i[2]=midx(k), hdr_f[3]=vmin, hdr_f[4]=vmax

__device__ __forceinline__ int bin_of(float x, float vmin, float scale, int NB) {
    int v = (int)((x - vmin) * scale);
    return v < 0 ? 0 : (v > NB - 1 ? NB - 1 : v);
}

// ---------------------------------------------------------------------------
// K1: parallel min/max reduction (float4) + tiny MLP. One 1024-thr block.
// ---------------------------------------------------------------------------
__global__ void __launch_bounds__(1024) k_setup(
    const float* __restrict__ atten, const float* __restrict__ md,
    const float* __restrict__ w1, const float* __restrict__ b1,
    const float* __restrict__ w2, const float* __restrict__ b2,
    int* __restrict__ hdr_i, float* __restrict__ hdr_f,
    int T, int n_out, int nTot)
{
    __shared__ float smin[16], smax[16];
    int tid = threadIdx.x;
    float vmin = 3.0e38f, vmax = -3.0e38f;
    int n4 = nTot >> 2;
    const float4* a4 = (const float4*)atten;
    for (int i = tid; i < n4; i += 1024) {
        float4 x = a4[i];
        vmin = fminf(vmin, fminf(fminf(x.x, x.y), fminf(x.z, x.w)));
        vmax = fmaxf(vmax, fmaxf(fmaxf(x.x, x.y), fmaxf(x.z, x.w)));
    }
    for (int i = (n4 << 2) + tid; i < nTot; i += 1024) {
        float x = atten[i];
        vmin = fminf(vmin, x); vmax = fmaxf(vmax, x);
    }
    #pragma unroll
    for (int off = 1; off < 64; off <<= 1) {
        vmin = fminf(vmin, __shfl_xor(vmin, off));
        vmax = fmaxf(vmax, __shfl_xor(vmax, off));
    }
    if ((tid & 63) == 0) { smin[tid >> 6] = vmin; smax[tid >> 6] = vmax; }
    __syncthreads();
    if (tid < 64) {
        int lane = tid;
        float m1 = (lane < 16) ? smin[lane] : 3.0e38f;
        float m2 = (lane < 16) ? smax[lane] : -3.0e38f;
        #pragma unroll
        for (int off = 1; off < 16; off <<= 1) {
            m1 = fminf(m1, __shfl_xor(m1, off));
            m2 = fmaxf(m2, __shfl_xor(m2, off));
        }
        int samples = 0;
        if (lane < 32) {                 // lane = b*16 + j
            int b = lane >> 4, j = lane & 15;
            float acc = b1[j];
            #pragma unroll
            for (int f = 0; f < 8; ++f) acc += md[b * 8 + f] * w1[f * 16 + j];
            float h = fmaxf(acc, 0.0f);
            float p = h * w2[j];
            #pragma unroll
            for (int off = 1; off < 16; off <<= 1) p += __shfl_xor(p, off);
            float s = p + b2[0];
            float factor = 1.0f / (1.0f + expf(-s));
            float hours = 4.0f + factor * (48.0f - 4.0f);
            samples = (int)(hours * 360.0f);
        }
        #pragma unroll
        for (int off = 1; off < 64; off <<= 1) samples = max(samples, __shfl_xor(samples, off));
        int mw = min(samples, T);
        // snap parity to harness-fixed n_out (guards float roundoff)
        int want_even = (n_out == T + 1) ? 1 : 0;
        if ((((mw & 1) == 0) ? 1 : 0) != want_even) { if (mw < T) mw += 1; else mw -= 1; }
        if (mw < 1) mw = 1;
        if (lane == 0) {
            hdr_i[0] = mw;
            hdr_i[1] = mw >> 1;
            hdr_i[2] = (mw - 1) >> 1;
            hdr_f[3] = m1;
            hdr_f[4] = m2;
        }
    }
}

// ---------------------------------------------------------------------------
// K2: binning + per-tile histogram. 4 element-tiles per 256-thr block
// (one LDS hist per wave). grid = ceil(2*NTe/4).
// ---------------------------------------------------------------------------
template<int NB>
__global__ void __launch_bounds__(256) k_hist(
    const float* __restrict__ atten, unsigned char* __restrict__ binIdx,
    unsigned short* __restrict__ tileCnt, const float* __restrict__ hdr_f,
    int T, int NTe)
{
    __shared__ unsigned int hist[4][NB];
    int wave = threadIdx.x >> 6;
    int lane = threadIdx.x & 63;
    int g = blockIdx.x * 4 + wave;           // global tile id over both batches
    bool valid = g < 2 * NTe;
    int b = g / NTe, tile = g - b * NTe;

    #pragma unroll
    for (int j = lane; j < NB; j += 64) hist[wave][j] = 0;
    __syncthreads();

    int t = tile * 64 + lane;
    if (valid && t < T) {
        float vmin = hdr_f[3], vmax = hdr_f[4];
        float scale = (float)NB / fmaxf(vmax - vmin, 1e-10f);
        float x = atten[(size_t)b * T + t];
        int v = bin_of(x, vmin, scale, NB);
        binIdx[(size_t)b * T + t] = (unsigned char)v;
        atomicAdd(&hist[wave][v], 1u);
    }
    __syncthreads();
    if (valid) {
        unsigned short* row = tileCnt + ((size_t)b * NTe + tile) * NB;
        #pragma unroll
        for (int j = lane; j < NB; j += 64) row[j] = (unsigned short)hist[wave][j];
    }
}

// ---------------------------------------------------------------------------
// K3: CDF writer, 16-record tiles. grid = 2*NTr16, 64 thr.
// F[t][v] = #{i<t: bin<=v} (u16, contiguous 2*NB-byte row).
// Base = coalesced tile-prefix over tileCnt + <=48-step catch-up, then 16
// serial record steps.
// ---------------------------------------------------------------------------
template<int NB>
__global__ void __launch_bounds__(64) k_cdf(
    const unsigned char* __restrict__ binIdx, const unsigned short* __restrict__ tileCnt,
    unsigned short* __restrict__ F, int T, int NTe, int NTr16)
{
    constexpr int VPL = NB / 64;   // bins per lane (contiguous)
    int blk = blockIdx.x;
    int b = blk / NTr16, r = blk - b * NTr16;
    int lane = threadIdx.x;
    int v0 = lane * VPL;
    int t0 = r * 16;

    int eb = t0 >> 6;          // whole element tiles strictly before t0
    int lead = t0 & 63;        // leading elements of partial tile

    // per-lane bin totals over tiles < eb (coalesced rows)
    int bs[VPL];
    #pragma unroll
    for (int kk = 0; kk < VPL; ++kk) bs[kk] = 0;
    const unsigned short* cb = tileCnt + (size_t)b * NTe * NB + v0;
    int rmax = eb < NTe ? eb : NTe;
    for (int rp = 0; rp < rmax; ++rp) {
        if (VPL == 4) {
            uint2 u = *(const uint2*)(cb + (size_t)rp * NB);
            bs[0] += (int)(u.x & 0xFFFFu); bs[1] += (int)(u.x >> 16);
            bs[2] += (int)(u.y & 0xFFFFu); bs[VPL - 1] += (int)(u.y >> 16);
        } else {
            bs[0] += (int)cb[(size_t)rp * NB];
        }
    }
    // inclusive scan over bins: local + wave prefix
    int c[VPL];
    int loc = 0;
    #pragma unroll
    for (int kk = 0; kk < VPL; ++kk) { loc += bs[kk]; c[kk] = loc; }
    int incl = loc;
    #pragma unroll
    for (int off = 1; off < 64; off <<= 1) {
        int n = __shfl_up(incl, off);
        if (lane >= off) incl += n;
    }
    int excl = incl - loc;
    #pragma unroll
    for (int kk = 0; kk < VPL; ++kk) c[kk] += excl;   // F[eb*64][v0+kk]

    const unsigned char* bi = binIdx + (size_t)b * T;

    // catch up over leading elements of the partial element-tile
    int myLead = (lane < lead && (eb * 64 + lane) < T) ? (int)bi[eb * 64 + lane] : 0;
    for (int j = 0; j < lead; ++j) {
        int bt = __shfl(myLead, j);
        #pragma unroll
        for (int kk = 0; kk < VPL; ++kk) c[kk] += (v0 + kk >= bt) ? 1 : 0;
    }

    // write 16 records
    int t1 = min(T + 1, t0 + 16);
    int myb = (lane < 16 && (t0 + lane) < T) ? (int)bi[t0 + lane] : 0;
    unsigned short* Fb = F + (size_t)b * (T + 1) * NB;
    for (int t = t0; t < t1; ++t) {
        unsigned short* Ft = Fb + (size_t)t * NB + v0;
        if (VPL == 4) {
            uint2 pk;
            pk.x = (unsigned)c[0] | ((unsigned)c[1] << 16);
            pk.y = (unsigned)c[2] | ((unsigned)c[VPL - 1] << 16);
            *(uint2*)Ft = pk;
        } else {
            Ft[0] = (unsigned short)c[0];
        }
        if (t < T) {
            int bt = __shfl(myb, t - t0);
            #pragma unroll
            for (int kk = 0; kk < VPL; ++kk) c[kk] += (v0 + kk >= bt) ? 1 : 0;
        }
    }
}

// ---------------------------------------------------------------------------
// K4: stable counting-sort scatter of values by (bin, t) -> bval.
// ---------------------------------------------------------------------------
template<int NB>
__global__ void __launch_bounds__(256) k_scatter(
    const float* __restrict__ atten, const unsigned char* __restrict__ binIdx,
    const unsigned short* __restrict__ F, float* __restrict__ bval, int T, int nTot)
{
    int i = blockIdx.x * 256 + threadIdx.x;
    if (i >= nTot) return;
    int b = i / T, t = i - b * T;
    int bn = binIdx[i];
    const unsigned short* Fb = F + (size_t)b * (T + 1) * NB;
    int s0   = bn ? (int)Fb[(size_t)T * NB + bn - 1] : 0;
    int FtB  = (int)Fb[(size_t)t * NB + bn];
    int FtP  = bn ? (int)Fb[(size_t)t * NB + bn - 1] : 0;
    bval[(size_t)b * T + (s0 + (FtB - FtP))] = atten[i];
}

// ---------------------------------------------------------------------------
// K5: wave-per-output query. Whole F rows at ta/tb loaded coalesced,
// ballot bin-select, register candidates, ballot bisection.
// ---------------------------------------------------------------------------
template<int NB>
__global__ void __launch_bounds__(256) k_query(
    const float* __restrict__ atten, const unsigned short* __restrict__ F,
    const float* __restrict__ bval,
    const int* __restrict__ hdr_i, const float* __restrict__ hdr_f,
    float* __restrict__ out, int T, int n_out)
{
    constexpr int VPL = NB / 64;
    int wid = (blockIdx.x * 256 + threadIdx.x) >> 6;
    int lane = threadIdx.x & 63;
    if (wid >= 2 * n_out) return;
    int b = wid / n_out, o = wid - b * n_out;

    int mw = hdr_i[0], pad = hdr_i[1], k = hdr_i[2];
    float vmin = hdr_f[3], vmax = hdr_f[4];
    float range = fmaxf(vmax - vmin, 1e-10f);
    float binw = range / (float)NB;
    float scale = (float)NB / range;

    int lo_t = o - pad;
    int ta = max(lo_t, 0);
    int tb = min(lo_t + mw, T);
    int L  = ta - lo_t;
    int Rr = lo_t + mw - tb;

    const float* xb = atten + (size_t)b * T;
    float x0 = xb[0], xT = xb[T - 1];
    int b0 = bin_of(x0, vmin, scale, NB);
    int bT = bin_of(xT, vmin, scale, NB);

    const unsigned short* Fb = F + (size_t)b * (T + 1) * NB;
    int fa[VPL], fb[VPL];
    {
        const unsigned short* pa = Fb + (size_t)ta * NB + lane * VPL;
        const unsigned short* pb = Fb + (size_t)tb * NB + lane * VPL;
        if (VPL == 4) {
            uint2 ua = *(const uint2*)pa;
            fa[0] = (int)(ua.x & 0xFFFFu); fa[1] = (int)(ua.x >> 16);
            fa[2] = (int)(ua.y & 0xFFFFu); fa[VPL - 1] = (int)(ua.y >> 16);
            uint2 ub = *(const uint2*)pb;
            fb[0] = (int)(ub.x & 0xFFFFu); fb[1] = (int)(ub.x >> 16);
            fb[2] = (int)(ub.y & 0xFFFFu); fb[VPL - 1] = (int)(ub.y >> 16);
        } else {
            fa[0] = (int)pa[0]; fb[0] = (int)pb[0];
        }
    }

    int kk = k + 1;
    int w[VPL];
    #pragma unroll
    for (int j = 0; j < VPL; ++j) {
        int v = lane * VPL + j;
        w[j] = fb[j] - fa[j] + (b0 <= v ? L : 0) + (bT <= v ? Rr : 0);
    }
    unsigned long long m = __ballot(w[VPL - 1] >= kk);
    int ll = (int)__ffsll(m) - 1;

    int wj[VPL], faj[VPL], fbj[VPL];
    #pragma unroll
    for (int j = 0; j < VPL; ++j) {
        wj[j]  = __shfl(w[j], ll);
        faj[j] = __shfl(fa[j], ll);
        fbj[j] = __shfl(fb[j], ll);
    }
    int wprevL  = __shfl(w[VPL - 1], ll - 1);
    int faPrevL = __shfl(fa[VPL - 1], ll - 1);
    int fbPrevL = __shfl(fb[VPL - 1], ll - 1);
    if (ll == 0) { wprevL = 0; faPrevL = 0; fbPrevL = 0; }

    int jj = VPL - 1;
    #pragma unroll
    for (int j = VPL - 1; j >= 0; --j) if (wj[j] >= kk) jj = j;
    int bsel = ll * VPL + jj;
    int wprev = jj > 0 ? wj[jj - 1] : wprevL;
    int faSel = faj[jj], fbSel = fbj[jj];
    int pA = jj > 0 ? faj[jj - 1] : faPrevL;
    int pB = jj > 0 ? fbj[jj - 1] : fbPrevL;

    int kp = k - wprev;
    int withinA = faSel - pA;
    int cntw = (fbSel - pB) - withinA;
    int s0 = bsel ? (int)Fb[(size_t)T * NB + bsel - 1] : 0;
    int j0 = s0 + withinA;
    int j1e = j0 + cntw;

    int Lc = (b0 == bsel) ? L : 0;
    int Rc = (bT == bsel) ? Rr : 0;

    const float* bv = bval + (size_t)b * T;
    float vlo = vmin + (float)bsel * binw - binw;
    float vhi = vmin + (float)(bsel + 1) * binw + binw;

    const int CAND = 4;
    float rr[CAND];
    bool reg = (cntw <= 64 * CAND);
    if (reg) {
        #pragma unroll
        for (int q = 0; q < CAND; ++q) {
            int idx = j0 + lane + q * 64;
            rr[q] = (idx < j1e) ? bv[idx] : 3.0e38f;
        }
    }
    int need = kp + 1;
    for (int it = 0; it < 18; ++it) {
        float vm = 0.5f * (vlo + vhi);
        int cnt = ((x0 < vm) ? Lc : 0) + ((xT < vm) ? Rc : 0);
        if (reg) {
            #pragma unroll
            for (int q = 0; q < CAND; ++q)
                cnt += __popcll(__ballot(rr[q] < vm));
        } else {
            int my = 0;
            for (int j = j0 + lane; j < j1e; j += 64) my += (bv[j] < vm) ? 1 : 0;
            #pragma unroll
            for (int off = 1; off < 64; off <<= 1) my += __shfl_xor(my, off);
            cnt += my;
        }
        if (cnt >= need) vhi = vm; else vlo = vm;
    }
    if (lane == 0) out[(size_t)b * n_out + o] = 0.5f * (vlo + vhi);
}

// ---------------------------------------------------------------------------
// Fallback (tiny d_ws): wave-per-output value bisection. Correct but slow.
// ---------------------------------------------------------------------------
__global__ void __launch_bounds__(256) k_fallback(
    const float* __restrict__ atten, const int* __restrict__ hdr_i,
    const float* __restrict__ hdr_f, float* __restrict__ out, int T, int n_out)
{
    int wave = threadIdx.x >> 6;
    int lane = threadIdx.x & 63;
    int gid = blockIdx.x * 4 + wave;
    if (gid >= 2 * n_out) return;
    int b = gid / n_out;
    int o = gid - b * n_out;
    int mw = hdr_i[0], pad = hdr_i[1], k = hdr_i[2];
    float lo = hdr_f[3] - 1e-3f, hi = hdr_f[4] + 1e-3f;
    const float* xb = atten + (size_t)b * T;
    int lo_t = o - pad;
    for (int it = 0; it < 26; ++it) {
        float vm = 0.5f * (lo + hi);
        int c = 0;
        for (int i = lane; i < mw; i += 64) {
            int t = lo_t + i;
            t = t < 0 ? 0 : (t >= T ? T - 1 : t);
            c += (xb[t] < vm) ? 1 : 0;
        }
        #pragma unroll
        for (int off = 1; off < 64; off <<= 1) c += __shfl_xor(c, off);
        if (c >= k + 1) hi = vm; else lo = vm;
    }
    if (lane == 0) out[(size_t)b * n_out + o] = 0.5f * (lo + hi);
}

// ---------------------------------------------------------------------------
struct Plan { size_t oBin, oCnt, oF, oV, total; };
static Plan make_plan(int NB, int nTot, int T, int NTe) {
    auto a64 = [](size_t x) { return (x + 63) & ~(size_t)63; };
    Plan p;
    size_t off = 64;
    p.oBin = off; off = a64(off + (size_t)nTot);
    p.oCnt = off; off = a64(off + (size_t)2 * NTe * NB * 2);
    p.oF   = off; off = a64(off + (size_t)2 * (T + 1) * NB * 2);
    p.oV   = off; off = a64(off + (size_t)nTot * 4);
    p.total = off;
    return p;
}

template<int NB>
static void run_pipeline(const float* atten, char* ws, const Plan& p,
                         const int* hdr_i, const float* hdr_f, float* out,
                         int T, int n_out, int nTot, int NTe,
                         hipStream_t stream)
{
    unsigned char*  binIdx  = (unsigned char*)(ws + p.oBin);
    unsigned short* tileCnt = (unsigned short*)(ws + p.oCnt);
    unsigned short* F       = (unsigned short*)(ws + p.oF);
    float*          bval    = (float*)(ws + p.oV);

    int NTr16 = (T + 1 + 15) / 16;
    int histBlocks = (2 * NTe + 3) / 4;
    k_hist<NB><<<dim3(histBlocks), dim3(256), 0, stream>>>(atten, binIdx, tileCnt, hdr_f, T, NTe);
    k_cdf<NB><<<dim3(2 * NTr16), dim3(64), 0, stream>>>(binIdx, tileCnt, F, T, NTe, NTr16);
    k_scatter<NB><<<dim3((nTot + 255) / 256), dim3(256), 0, stream>>>(atten, binIdx, F, bval, T, nTot);
    int nWaves = 2 * n_out;
    k_query<NB><<<dim3((nWaves + 3) / 4), dim3(256), 0, stream>>>(atten, F, bval, hdr_i, hdr_f, out, T, n_out);
}

extern "C" void kernel_launch(void* const* d_in, const int* in_sizes, int n_in,
                              void* d_out, int out_size, void* d_ws, size_t ws_size,
                              hipStream_t stream)
{
    const float* atten = (const float*)d_in[0];
    const float* md    = (const float*)d_in[1];
    const float* w1    = (const float*)d_in[2];
    const float* b1    = (const float*)d_in[3];
    const float* w2    = (const float*)d_in[4];
    const float* b2    = (const float*)d_in[5];
    float* out = (float*)d_out;

    const int B = 2;
    const int nTot  = in_sizes[0];
    const int T     = nTot / B;
    const int n_out = out_size / B;
    const int NTe = (T + 63) / 64;        // element tiles

    char* ws = (char*)d_ws;
    int*   hdr_i = (int*)ws;
    float* hdr_f = (float*)ws;

    k_setup<<<dim3(1), dim3(1024), 0, stream>>>(atten, md, w1, b1, w2, b2,
                                                hdr_i, hdr_f, T, n_out, nTot);

    Plan p256 = make_plan(256, nTot, T, NTe);
    Plan p64  = make_plan(64,  nTot, T, NTe);
    if (ws_size >= p256.total) {
        run_pipeline<256>(atten, ws, p256, hdr_i, hdr_f, out, T, n_out, nTot, NTe, stream);
    } else if (ws_size >= p64.total) {
        run_pipeline<64>(atten, ws, p64, hdr_i, hdr_f, out, T, n_out, nTot, NTe, stream);
    } else {
        int blocks = (2 * n_out + 3) / 4;
        k_fallback<<<dim3(blocks), dim3(256), 0, stream>>>(atten, hdr_i, hdr_f, out, T, n_out);
    }
}

// Round 5
// 104.462 us; speedup vs baseline: 2.7006x; 1.2380x over previous
//
#include <hip/hip_runtime.h>
#include <math.h>

// ws header: hdr_i[0]=mw, hdr_i[1]=pad, hdr_i[2]=midx(k), hdr_f[3]=vmin, hdr_f[4]=vmax

__device__ __forceinline__ int bin_of(float x, float vmin, float scale, int NB) {
    int v = (int)((x - vmin) * scale);
    return v < 0 ? 0 : (v > NB - 1 ? NB - 1 : v);
}

// ---------------------------------------------------------------------------
// K1: parallel min/max reduction (float4) + tiny MLP. One 1024-thr block.
// ---------------------------------------------------------------------------
__global__ void __launch_bounds__(1024) k_setup(
    const float* __restrict__ atten, const float* __restrict__ md,
    const float* __restrict__ w1, const float* __restrict__ b1,
    const float* __restrict__ w2, const float* __restrict__ b2,
    int* __restrict__ hdr_i, float* __restrict__ hdr_f,
    int T, int n_out, int nTot)
{
    __shared__ float smin[16], smax[16];
    int tid = threadIdx.x;
    float vmin = 3.0e38f, vmax = -3.0e38f;
    int n4 = nTot >> 2;
    const float4* a4 = (const float4*)atten;
    for (int i = tid; i < n4; i += 1024) {
        float4 x = a4[i];
        vmin = fminf(vmin, fminf(fminf(x.x, x.y), fminf(x.z, x.w)));
        vmax = fmaxf(vmax, fmaxf(fmaxf(x.x, x.y), fmaxf(x.z, x.w)));
    }
    for (int i = (n4 << 2) + tid; i < nTot; i += 1024) {
        float x = atten[i];
        vmin = fminf(vmin, x); vmax = fmaxf(vmax, x);
    }
    #pragma unroll
    for (int off = 1; off < 64; off <<= 1) {
        vmin = fminf(vmin, __shfl_xor(vmin, off));
        vmax = fmaxf(vmax, __shfl_xor(vmax, off));
    }
    if ((tid & 63) == 0) { smin[tid >> 6] = vmin; smax[tid >> 6] = vmax; }
    __syncthreads();
    if (tid < 64) {
        int lane = tid;
        float m1 = (lane < 16) ? smin[lane] : 3.0e38f;
        float m2 = (lane < 16) ? smax[lane] : -3.0e38f;
        #pragma unroll
        for (int off = 1; off < 16; off <<= 1) {
            m1 = fminf(m1, __shfl_xor(m1, off));
            m2 = fmaxf(m2, __shfl_xor(m2, off));
        }
        int samples = 0;
        if (lane < 32) {                 // lane = b*16 + j
            int b = lane >> 4, j = lane & 15;
            float acc = b1[j];
            #pragma unroll
            for (int f = 0; f < 8; ++f) acc += md[b * 8 + f] * w1[f * 16 + j];
            float h = fmaxf(acc, 0.0f);
            float p = h * w2[j];
            #pragma unroll
            for (int off = 1; off < 16; off <<= 1) p += __shfl_xor(p, off);
            float s = p + b2[0];
            float factor = 1.0f / (1.0f + expf(-s));
            float hours = 4.0f + factor * (48.0f - 4.0f);
            samples = (int)(hours * 360.0f);
        }
        #pragma unroll
        for (int off = 1; off < 64; off <<= 1) samples = max(samples, __shfl_xor(samples, off));
        int mw = min(samples, T);
        // snap parity to harness-fixed n_out (guards float roundoff)
        int want_even = (n_out == T + 1) ? 1 : 0;
        if ((((mw & 1) == 0) ? 1 : 0) != want_even) { if (mw < T) mw += 1; else mw -= 1; }
        if (mw < 1) mw = 1;
        if (lane == 0) {
            hdr_i[0] = mw;
            hdr_i[1] = mw >> 1;
            hdr_i[2] = (mw - 1) >> 1;
            hdr_f[3] = m1;
            hdr_f[4] = m2;
        }
    }
}

// ---------------------------------------------------------------------------
// K2: binning + per-tile histogram. 4 element-tiles per 256-thr block
// (one LDS hist per wave). grid = ceil(2*NTe/4).
// ---------------------------------------------------------------------------
template<int NB>
__global__ void __launch_bounds__(256) k_hist(
    const float* __restrict__ atten, unsigned char* __restrict__ binIdx,
    unsigned short* __restrict__ tileCnt, const float* __restrict__ hdr_f,
    int T, int NTe)
{
    __shared__ unsigned int hist[4][NB];
    int wave = threadIdx.x >> 6;
    int lane = threadIdx.x & 63;
    int g = blockIdx.x * 4 + wave;           // global tile id over both batches
    bool valid = g < 2 * NTe;
    int b = g / NTe, tile = g - b * NTe;

    #pragma unroll
    for (int j = lane; j < NB; j += 64) hist[wave][j] = 0;
    __syncthreads();

    int t = tile * 64 + lane;
    if (valid && t < T) {
        float vmin = hdr_f[3], vmax = hdr_f[4];
        float scale = (float)NB / fmaxf(vmax - vmin, 1e-10f);
        float x = atten[(size_t)b * T + t];
        int v = bin_of(x, vmin, scale, NB);
        binIdx[(size_t)b * T + t] = (unsigned char)v;
        atomicAdd(&hist[wave][v], 1u);
    }
    __syncthreads();
    if (valid) {
        unsigned short* row = tileCnt + ((size_t)b * NTe + tile) * NB;
        #pragma unroll
        for (int j = lane; j < NB; j += 64) row[j] = (unsigned short)hist[wave][j];
    }
}

// ---------------------------------------------------------------------------
// K3: CDF writer, 16-record tiles. grid = 2*NTr16, 64 thr.
// F[t][v] = #{i<t: bin<=v} (u16, contiguous 2*NB-byte row).
// Tile-prefix loop is unrolled x8 with independent PACKED u32 accumulators:
// 8 loads in flight per waitcnt (breaks the serial load-latency chain that
// pinned R4 at 41.6us), and u16-pair adds carry-free since totals <= T < 2^16.
// ---------------------------------------------------------------------------
template<int NB>
__global__ void __launch_bounds__(64) k_cdf(
    const unsigned char* __restrict__ binIdx, const unsigned short* __restrict__ tileCnt,
    unsigned short* __restrict__ F, int T, int NTe, int NTr16)
{
    constexpr int VPL = NB / 64;   // bins per lane (contiguous)
    int blk = blockIdx.x;
    int b = blk / NTr16, r = blk - b * NTr16;
    int lane = threadIdx.x;
    int v0 = lane * VPL;
    int t0 = r * 16;

    int eb = t0 >> 6;          // whole element tiles strictly before t0
    int lead = t0 & 63;        // leading elements of partial tile

    int bs[VPL];
    #pragma unroll
    for (int kk = 0; kk < VPL; ++kk) bs[kk] = 0;
    int rmax = eb < NTe ? eb : NTe;

    if (VPL == 4) {
        // packed u32 accumulation over uint2 rows, 8 independent chains
        const uint2* cb2 = (const uint2*)(tileCnt + (size_t)b * NTe * NB) + lane;
        const int stride = NB / 4;           // uint2 per row
        unsigned ax[8], ay[8];
        #pragma unroll
        for (int q = 0; q < 8; ++q) { ax[q] = 0u; ay[q] = 0u; }
        int rp = 0;
        for (; rp + 8 <= rmax; rp += 8) {
            #pragma unroll
            for (int q = 0; q < 8; ++q) {
                uint2 u = cb2[(size_t)(rp + q) * stride];
                ax[q] += u.x; ay[q] += u.y;
            }
        }
        for (; rp < rmax; ++rp) {
            uint2 u = cb2[(size_t)rp * stride];
            ax[0] += u.x; ay[0] += u.y;
        }
        unsigned sx = 0, sy = 0;
        #pragma unroll
        for (int q = 0; q < 8; ++q) { sx += ax[q]; sy += ay[q]; }
        bs[0] = (int)(sx & 0xFFFFu); bs[1] = (int)(sx >> 16);
        bs[2] = (int)(sy & 0xFFFFu); bs[VPL - 1] = (int)(sy >> 16);
    } else {
        const unsigned short* cb = tileCnt + (size_t)b * NTe * NB + v0;
        int a[8];
        #pragma unroll
        for (int q = 0; q < 8; ++q) a[q] = 0;
        int rp = 0;
        for (; rp + 8 <= rmax; rp += 8) {
            #pragma unroll
            for (int q = 0; q < 8; ++q) a[q] += (int)cb[(size_t)(rp + q) * NB];
        }
        for (; rp < rmax; ++rp) a[0] += (int)cb[(size_t)rp * NB];
        #pragma unroll
        for (int q = 1; q < 8; ++q) a[0] += a[q];
        bs[0] = a[0];
    }

    // inclusive scan over bins: local + wave prefix
    int c[VPL];
    int loc = 0;
    #pragma unroll
    for (int kk = 0; kk < VPL; ++kk) { loc += bs[kk]; c[kk] = loc; }
    int incl = loc;
    #pragma unroll
    for (int off = 1; off < 64; off <<= 1) {
        int n = __shfl_up(incl, off);
        if (lane >= off) incl += n;
    }
    int excl = incl - loc;
    #pragma unroll
    for (int kk = 0; kk < VPL; ++kk) c[kk] += excl;   // F[eb*64][v0+kk]

    const unsigned char* bi = binIdx + (size_t)b * T;

    // catch up over leading elements of the partial element-tile
    int myLead = (lane < lead && (eb * 64 + lane) < T) ? (int)bi[eb * 64 + lane] : 0;
    for (int j = 0; j < lead; ++j) {
        int bt = __shfl(myLead, j);
        #pragma unroll
        for (int kk = 0; kk < VPL; ++kk) c[kk] += (v0 + kk >= bt) ? 1 : 0;
    }

    // write 16 records
    int t1 = min(T + 1, t0 + 16);
    int myb = (lane < 16 && (t0 + lane) < T) ? (int)bi[t0 + lane] : 0;
    unsigned short* Fb = F + (size_t)b * (T + 1) * NB;
    for (int t = t0; t < t1; ++t) {
        unsigned short* Ft = Fb + (size_t)t * NB + v0;
        if (VPL == 4) {
            uint2 pk;
            pk.x = (unsigned)c[0] | ((unsigned)c[1] << 16);
            pk.y = (unsigned)c[2] | ((unsigned)c[VPL - 1] << 16);
            *(uint2*)Ft = pk;
        } else {
            Ft[0] = (unsigned short)c[0];
        }
        if (t < T) {
            int bt = __shfl(myb, t - t0);
            #pragma unroll
            for (int kk = 0; kk < VPL; ++kk) c[kk] += (v0 + kk >= bt) ? 1 : 0;
        }
    }
}

// ---------------------------------------------------------------------------
// K4: stable counting-sort scatter of values by (bin, t) -> bval.
// ---------------------------------------------------------------------------
template<int NB>
__global__ void __launch_bounds__(256) k_scatter(
    const float* __restrict__ atten, const unsigned char* __restrict__ binIdx,
    const unsigned short* __restrict__ F, float* __restrict__ bval, int T, int nTot)
{
    int i = blockIdx.x * 256 + threadIdx.x;
    if (i >= nTot) return;
    int b = i / T, t = i - b * T;
    int bn = binIdx[i];
    const unsigned short* Fb = F + (size_t)b * (T + 1) * NB;
    int s0   = bn ? (int)Fb[(size_t)T * NB + bn - 1] : 0;
    int FtB  = (int)Fb[(size_t)t * NB + bn];
    int FtP  = bn ? (int)Fb[(size_t)t * NB + bn - 1] : 0;
    bval[(size_t)b * T + (s0 + (FtB - FtP))] = atten[i];
}

// ---------------------------------------------------------------------------
// K5: wave-per-output query. Whole F rows at ta/tb loaded coalesced,
// ballot bin-select, register candidates, ballot bisection.
// ---------------------------------------------------------------------------
template<int NB>
__global__ void __launch_bounds__(256) k_query(
    const float* __restrict__ atten, const unsigned short* __restrict__ F,
    const float* __restrict__ bval,
    const int* __restrict__ hdr_i, const float* __restrict__ hdr_f,
    float* __restrict__ out, int T, int n_out)
{
    constexpr int VPL = NB / 64;
    int wid = (blockIdx.x * 256 + threadIdx.x) >> 6;
    int lane = threadIdx.x & 63;
    if (wid >= 2 * n_out) return;
    int b = wid / n_out, o = wid - b * n_out;

    int mw = hdr_i[0], pad = hdr_i[1], k = hdr_i[2];
    float vmin = hdr_f[3], vmax = hdr_f[4];
    float range = fmaxf(vmax - vmin, 1e-10f);
    float binw = range / (float)NB;
    float scale = (float)NB / range;

    int lo_t = o - pad;
    int ta = max(lo_t, 0);
    int tb = min(lo_t + mw, T);
    int L  = ta - lo_t;
    int Rr = lo_t + mw - tb;

    const float* xb = atten + (size_t)b * T;
    float x0 = xb[0], xT = xb[T - 1];
    int b0 = bin_of(x0, vmin, scale, NB);
    int bT = bin_of(xT, vmin, scale, NB);

    const unsigned short* Fb = F + (size_t)b * (T + 1) * NB;
    int fa[VPL], fb[VPL];
    {
        const unsigned short* pa = Fb + (size_t)ta * NB + lane * VPL;
        const unsigned short* pb = Fb + (size_t)tb * NB + lane * VPL;
        if (VPL == 4) {
            uint2 ua = *(const uint2*)pa;
            fa[0] = (int)(ua.x & 0xFFFFu); fa[1] = (int)(ua.x >> 16);
            fa[2] = (int)(ua.y & 0xFFFFu); fa[VPL - 1] = (int)(ua.y >> 16);
            uint2 ub = *(const uint2*)pb;
            fb[0] = (int)(ub.x & 0xFFFFu); fb[1] = (int)(ub.x >> 16);
            fb[2] = (int)(ub.y & 0xFFFFu); fb[VPL - 1] = (int)(ub.y >> 16);
        } else {
            fa[0] = (int)pa[0]; fb[0] = (int)pb[0];
        }
    }

    int kk = k + 1;
    int w[VPL];
    #pragma unroll
    for (int j = 0; j < VPL; ++j) {
        int v = lane * VPL + j;
        w[j] = fb[j] - fa[j] + (b0 <= v ? L : 0) + (bT <= v ? Rr : 0);
    }
    unsigned long long m = __ballot(w[VPL - 1] >= kk);
    int ll = (int)__ffsll(m) - 1;

    int wj[VPL], faj[VPL], fbj[VPL];
    #pragma unroll
    for (int j = 0; j < VPL; ++j) {
        wj[j]  = __shfl(w[j], ll);
        faj[j] = __shfl(fa[j], ll);
        fbj[j] = __shfl(fb[j], ll);
    }
    int wprevL  = __shfl(w[VPL - 1], ll - 1);
    int faPrevL = __shfl(fa[VPL - 1], ll - 1);
    int fbPrevL = __shfl(fb[VPL - 1], ll - 1);
    if (ll == 0) { wprevL = 0; faPrevL = 0; fbPrevL = 0; }

    int jj = VPL - 1;
    #pragma unroll
    for (int j = VPL - 1; j >= 0; --j) if (wj[j] >= kk) jj = j;
    int bsel = ll * VPL + jj;
    int wprev = jj > 0 ? wj[jj - 1] : wprevL;
    int faSel = faj[jj], fbSel = fbj[jj];
    int pA = jj > 0 ? faj[jj - 1] : faPrevL;
    int pB = jj > 0 ? fbj[jj - 1] : fbPrevL;

    int kp = k - wprev;
    int withinA = faSel - pA;
    int cntw = (fbSel - pB) - withinA;
    int s0 = bsel ? (int)Fb[(size_t)T * NB + bsel - 1] : 0;
    int j0 = s0 + withinA;
    int j1e = j0 + cntw;

    int Lc = (b0 == bsel) ? L : 0;
    int Rc = (bT == bsel) ? Rr : 0;

    const float* bv = bval + (size_t)b * T;
    float vlo = vmin + (float)bsel * binw - binw;
    float vhi = vmin + (float)(bsel + 1) * binw + binw;

    const int CAND = 4;
    float rr[CAND];
    bool reg = (cntw <= 64 * CAND);
    if (reg) {
        #pragma unroll
        for (int q = 0; q < CAND; ++q) {
            int idx = j0 + lane + q * 64;
            rr[q] = (idx < j1e) ? bv[idx] : 3.0e38f;
        }
    }
    int need = kp + 1;
    for (int it = 0; it < 18; ++it) {
        float vm = 0.5f * (vlo + vhi);
        int cnt = ((x0 < vm) ? Lc : 0) + ((xT < vm) ? Rc : 0);
        if (reg) {
            #pragma unroll
            for (int q = 0; q < CAND; ++q)
                cnt += __popcll(__ballot(rr[q] < vm));
        } else {
            int my = 0;
            for (int j = j0 + lane; j < j1e; j += 64) my += (bv[j] < vm) ? 1 : 0;
            #pragma unroll
            for (int off = 1; off < 64; off <<= 1) my += __shfl_xor(my, off);
            cnt += my;
        }
        if (cnt >= need) vhi = vm; else vlo = vm;
    }
    if (lane == 0) out[(size_t)b * n_out + o] = 0.5f * (vlo + vhi);
}

// ---------------------------------------------------------------------------
// Fallback (tiny d_ws): wave-per-output value bisection. Correct but slow.
// ---------------------------------------------------------------------------
__global__ void __launch_bounds__(256) k_fallback(
    const float* __restrict__ atten, const int* __restrict__ hdr_i,
    const float* __restrict__ hdr_f, float* __restrict__ out, int T, int n_out)
{
    int wave = threadIdx.x >> 6;
    int lane = threadIdx.x & 63;
    int gid = blockIdx.x * 4 + wave;
    if (gid >= 2 * n_out) return;
    int b = gid / n_out;
    int o = gid - b * n_out;
    int mw = hdr_i[0], pad = hdr_i[1], k = hdr_i[2];
    float lo = hdr_f[3] - 1e-3f, hi = hdr_f[4] + 1e-3f;
    const float* xb = atten + (size_t)b * T;
    int lo_t = o - pad;
    for (int it = 0; it < 26; ++it) {
        float vm = 0.5f * (lo + hi);
        int c = 0;
        for (int i = lane; i < mw; i += 64) {
            int t = lo_t + i;
            t = t < 0 ? 0 : (t >= T ? T - 1 : t);
            c += (xb[t] < vm) ? 1 : 0;
        }
        #pragma unroll
        for (int off = 1; off < 64; off <<= 1) c += __shfl_xor(c, off);
        if (c >= k + 1) hi = vm; else lo = vm;
    }
    if (lane == 0) out[(size_t)b * n_out + o] = 0.5f * (lo + hi);
}

// ---------------------------------------------------------------------------
struct Plan { size_t oBin, oCnt, oF, oV, total; };
static Plan make_plan(int NB, int nTot, int T, int NTe) {
    auto a64 = [](size_t x) { return (x + 63) & ~(size_t)63; };
    Plan p;
    size_t off = 64;
    p.oBin = off; off = a64(off + (size_t)nTot);
    p.oCnt = off; off = a64(off + (size_t)2 * NTe * NB * 2);
    p.oF   = off; off = a64(off + (size_t)2 * (T + 1) * NB * 2);
    p.oV   = off; off = a64(off + (size_t)nTot * 4);
    p.total = off;
    return p;
}

template<int NB>
static void run_pipeline(const float* atten, char* ws, const Plan& p,
                         const int* hdr_i, const float* hdr_f, float* out,
                         int T, int n_out, int nTot, int NTe,
                         hipStream_t stream)
{
    unsigned char*  binIdx  = (unsigned char*)(ws + p.oBin);
    unsigned short* tileCnt = (unsigned short*)(ws + p.oCnt);
    unsigned short* F       = (unsigned short*)(ws + p.oF);
    float*          bval    = (float*)(ws + p.oV);

    int NTr16 = (T + 1 + 15) / 16;
    int histBlocks = (2 * NTe + 3) / 4;
    k_hist<NB><<<dim3(histBlocks), dim3(256), 0, stream>>>(atten, binIdx, tileCnt, hdr_f, T, NTe);
    k_cdf<NB><<<dim3(2 * NTr16), dim3(64), 0, stream>>>(binIdx, tileCnt, F, T, NTe, NTr16);
    k_scatter<NB><<<dim3((nTot + 255) / 256), dim3(256), 0, stream>>>(atten, binIdx, F, bval, T, nTot);
    int nWaves = 2 * n_out;
    k_query<NB><<<dim3((nWaves + 3) / 4), dim3(256), 0, stream>>>(atten, F, bval, hdr_i, hdr_f, out, T, n_out);
}

extern "C" void kernel_launch(void* const* d_in, const int* in_sizes, int n_in,
                              void* d_out, int out_size, void* d_ws, size_t ws_size,
                              hipStream_t stream)
{
    const float* atten = (const float*)d_in[0];
    const float* md    = (const float*)d_in[1];
    const float* w1    = (const float*)d_in[2];
    const float* b1    = (const float*)d_in[3];
    const float* w2    = (const float*)d_in[4];
    const float* b2    = (const float*)d_in[5];
    float* out = (float*)d_out;

    const int B = 2;
    const int nTot  = in_sizes[0];
    const int T     = nTot / B;
    const int n_out = out_size / B;
    const int NTe = (T + 63) / 64;        // element tiles

    char* ws = (char*)d_ws;
    int*   hdr_i = (int*)ws;
    float* hdr_f = (float*)ws;

    k_setup<<<dim3(1), dim3(1024), 0, stream>>>(atten, md, w1, b1, w2, b2,
                                                hdr_i, hdr_f, T, n_out, nTot);

    Plan p256 = make_plan(256, nTot, T, NTe);
    Plan p64  = make_plan(64,  nTot, T, NTe);
    if (ws_size >= p256.total) {
        run_pipeline<256>(atten, ws, p256, hdr_i, hdr_f, out, T, n_out, nTot, NTe, stream);
    } else if (ws_size >= p64.total) {
        run_pipeline<64>(atten, ws, p64, hdr_i, hdr_f, out, T, n_out, nTot, NTe, stream);
    } else {
        int blocks = (2 * n_out + 3) / 4;
        k_fallback<<<dim3(blocks), dim3(256), 0, stream>>>(atten, hdr_i, hdr_f, out, T, n_out);
    }
}